// Round 3
// baseline (11345.912 us; speedup 1.0000x reference)
//
#include <hip/hip_runtime.h>

typedef unsigned short u16t;
typedef __attribute__((ext_vector_type(4))) unsigned short us4;
typedef __attribute__((ext_vector_type(8))) unsigned short us8;

#define NB 16
#define KL 2048
#define QL 1024
#define EE 512
#define NH 8
#define DH 64

__device__ __forceinline__ float b2f(u16t u) {
  return __uint_as_float(((unsigned)u) << 16);
}
__device__ __forceinline__ u16t f2b(float f) {
  unsigned u = __float_as_uint(f);
  u += 0x7fffu + ((u >> 16) & 1u);
  return (u16t)(u >> 16);
}

// ---------------- QKV projection: A,W fp32; scatter bf16 into [B,H,S,DH] ---
__global__ __launch_bounds__(256) void gemm_qkv(
    const float* __restrict__ A, const float* __restrict__ W,
    const float* __restrict__ bias, u16t* __restrict__ q_ws,
    u16t* __restrict__ k_ws, u16t* __restrict__ v_ws) {
  __shared__ float As[32][64];
  __shared__ float Bs[32][64];
  const int Kd = EE;
  int t = threadIdx.x;
  int n0 = blockIdx.x * 64, m0 = blockIdx.y * 64;
  int tx = t & 15, ty = t >> 4;
  int lr = t >> 2, lc = (t & 3) * 8;
  float acc[4][4] = {};
  for (int kc = 0; kc < Kd; kc += 32) {
    float4 a0 = *(const float4*)&A[(m0 + lr) * Kd + kc + lc];
    float4 a1 = *(const float4*)&A[(m0 + lr) * Kd + kc + lc + 4];
    float4 w0 = *(const float4*)&W[(n0 + lr) * Kd + kc + lc];
    float4 w1 = *(const float4*)&W[(n0 + lr) * Kd + kc + lc + 4];
    __syncthreads();
    As[lc + 0][lr] = a0.x; As[lc + 1][lr] = a0.y;
    As[lc + 2][lr] = a0.z; As[lc + 3][lr] = a0.w;
    As[lc + 4][lr] = a1.x; As[lc + 5][lr] = a1.y;
    As[lc + 6][lr] = a1.z; As[lc + 7][lr] = a1.w;
    Bs[lc + 0][lr] = w0.x; Bs[lc + 1][lr] = w0.y;
    Bs[lc + 2][lr] = w0.z; Bs[lc + 3][lr] = w0.w;
    Bs[lc + 4][lr] = w1.x; Bs[lc + 5][lr] = w1.y;
    Bs[lc + 6][lr] = w1.z; Bs[lc + 7][lr] = w1.w;
    __syncthreads();
#pragma unroll
    for (int k = 0; k < 32; ++k) {
      float4 a = *(float4*)&As[k][ty * 4];
      float4 b = *(float4*)&Bs[k][tx * 4];
      float ar[4] = {a.x, a.y, a.z, a.w};
      float br[4] = {b.x, b.y, b.z, b.w};
#pragma unroll
      for (int i = 0; i < 4; ++i)
#pragma unroll
        for (int j = 0; j < 4; ++j) acc[i][j] += ar[i] * br[j];
    }
  }
  int sec = n0 >> 9;       // 0=q, 1=k, 2=v (uniform per block)
  int hh = (n0 >> 6) & 7;  // head (uniform per block)
#pragma unroll
  for (int i = 0; i < 4; ++i) {
    int m = m0 + ty * 4 + i;
    int bb_ = m >> 11, pos = m & 2047;
#pragma unroll
    for (int j = 0; j < 4; ++j) {
      int n = n0 + tx * 4 + j;
      int dd = n & 63;
      u16t o = f2b(acc[i][j] + bias[n]);
      if (sec == 0) {
        if (pos >= QL) q_ws[((bb_ * NH + hh) * QL + pos - QL) * DH + dd] = o;
      } else if (sec == 1) {
        k_ws[((bb_ * NH + hh) * KL + pos) * DH + dd] = o;
      } else {
        v_ws[((bb_ * NH + hh) * KL + pos) * DH + dd] = o;
      }
    }
  }
}

// ---- tiled GEMM: C[M,N] = A[M,K](bf16) @ W[N,K](fp32)^T + bias, C bf16 ----
__global__ __launch_bounds__(256) void gemm_bias(
    const u16t* __restrict__ A, const float* __restrict__ W,
    const float* __restrict__ bias, u16t* __restrict__ C,
    int M, int N, int Kd, int relu) {
  __shared__ float As[32][64];
  __shared__ float Bs[32][64];
  int t = threadIdx.x;
  int n0 = blockIdx.x * 64, m0 = blockIdx.y * 64;
  int tx = t & 15, ty = t >> 4;
  int lr = t >> 2, lc = (t & 3) * 8;
  float acc[4][4] = {};
  for (int kc = 0; kc < Kd; kc += 32) {
    us8 av = *(const us8*)&A[(m0 + lr) * Kd + kc + lc];
    float4 w0 = *(const float4*)&W[(n0 + lr) * Kd + kc + lc];
    float4 w1 = *(const float4*)&W[(n0 + lr) * Kd + kc + lc + 4];
    __syncthreads();
#pragma unroll
    for (int j = 0; j < 8; ++j) As[lc + j][lr] = b2f(av[j]);
    Bs[lc + 0][lr] = w0.x; Bs[lc + 1][lr] = w0.y;
    Bs[lc + 2][lr] = w0.z; Bs[lc + 3][lr] = w0.w;
    Bs[lc + 4][lr] = w1.x; Bs[lc + 5][lr] = w1.y;
    Bs[lc + 6][lr] = w1.z; Bs[lc + 7][lr] = w1.w;
    __syncthreads();
#pragma unroll
    for (int k = 0; k < 32; ++k) {
      float4 a = *(float4*)&As[k][ty * 4];
      float4 b = *(float4*)&Bs[k][tx * 4];
      float ar[4] = {a.x, a.y, a.z, a.w};
      float br[4] = {b.x, b.y, b.z, b.w};
#pragma unroll
      for (int i = 0; i < 4; ++i)
#pragma unroll
        for (int j = 0; j < 4; ++j) acc[i][j] += ar[i] * br[j];
    }
  }
#pragma unroll
  for (int i = 0; i < 4; ++i) {
    int m = m0 + ty * 4 + i;
#pragma unroll
    for (int j = 0; j < 4; ++j) {
      int n = n0 + tx * 4 + j;
      float v = acc[i][j] + bias[n];
      if (relu) v = fmaxf(v, 0.f);
      C[m * N + n] = f2b(v);
    }
  }
}

// ---------------- attention: block = (b, 8 query rows), all heads in-block -
__global__ __launch_bounds__(256) void attn_kernel(
    const u16t* __restrict__ qw, const u16t* __restrict__ kw,
    const u16t* __restrict__ vw, const int* kpm_i,
    const unsigned char* kpm_b, u16t* __restrict__ ctx_out,
    float* __restrict__ aw_out) {
  const int b = blockIdx.y;
  const int q0 = blockIdx.x * 8;
  const int t = threadIdx.x;
  const int lane = t & 63, wid = t >> 6;
  const float NEG = -1.0e30f;  // finite sentinel: no inf anywhere

  __shared__ float q_lds[8 * 64];
  __shared__ float p_lds[8 * 1024];  // P published in two 1024-wide halves
  __shared__ float ctxp[4 * 8 * 64];
  __shared__ float red[32];
  __shared__ float mrow[8], lrow[8];
  __shared__ int mode_s;

  // runtime mask-dtype detection: 0=byte bool, 1=int32, 2=int64. OOB-safe
  // (reads 256 B; mask buffer is >= 32768 B in every interpretation).
  if (t == 0) {
    bool small = true, oddzero = true, evenone = false;
    for (int i = 0; i < 64; ++i) {
      unsigned v = (unsigned)kpm_i[i];
      if (v > 1u) small = false;
      if ((i & 1) && v != 0u) oddzero = false;
      if (!(i & 1) && v == 1u) evenone = true;
    }
    mode_s = !small ? 0 : ((oddzero && evenone) ? 2 : 1);
  }
  __syncthreads();
  const int mode = mode_s;

  bool padf[8];
#pragma unroll
  for (int j = 0; j < 8; ++j) {
    int k = t + 256 * j;
    int idx = b * KL + k;
    padf[j] = (mode == 0)
                  ? (kpm_b[idx] != 0)
                  : (mode == 1 ? (kpm_i[idx] != 0) : (kpm_i[2 * idx] != 0));
  }

  float aw[8][8] = {};

  for (int h = 0; h < NH; ++h) {
    // stage Q tile (8 rows x 64) as fp32
    for (int i = t; i < 512; i += 256) {
      int qi = i >> 6, d = i & 63;
      q_lds[i] = b2f(qw[((b * NH + h) * QL + q0 + qi) * DH + d]);
    }
    __syncthreads();

    // scores: thread owns k = t + 256*j, all 8 query rows
    float s[8][8] = {};
    const int kbase = ((b * NH + h) * KL) * DH;
#pragma unroll
    for (int dc = 0; dc < 64; dc += 4) {
      float kf[8][4];
#pragma unroll
      for (int j = 0; j < 8; ++j) {
        us4 kr = *(const us4*)&kw[kbase + (t + 256 * j) * DH + dc];
#pragma unroll
        for (int i = 0; i < 4; ++i) kf[j][i] = b2f(kr[i]);
      }
#pragma unroll
      for (int qi = 0; qi < 8; ++qi) {
        float4 qa = *(float4*)&q_lds[qi * 64 + dc];
#pragma unroll
        for (int j = 0; j < 8; ++j)
          s[qi][j] += qa.x * kf[j][0] + qa.y * kf[j][1] + qa.z * kf[j][2] +
                      qa.w * kf[j][3];
      }
    }

    // mask + scale (scale = dh^-0.5 = 0.125)
#pragma unroll
    for (int qi = 0; qi < 8; ++qi) {
      int r = q0 + qi;
#pragma unroll
      for (int j = 0; j < 8; ++j) {
        int k = t + 256 * j;
        bool allowed = (k <= r + QL) && (!padf[j] || k == r + QL);
        s[qi][j] = allowed ? s[qi][j] * 0.125f : NEG;
      }
    }

    // row max (exact softmax, two-pass)
    float pm[8];
#pragma unroll
    for (int qi = 0; qi < 8; ++qi) {
      float m = s[qi][0];
#pragma unroll
      for (int j = 1; j < 8; ++j) m = fmaxf(m, s[qi][j]);
      pm[qi] = m;
    }
#pragma unroll
    for (int off = 32; off > 0; off >>= 1)
#pragma unroll
      for (int qi = 0; qi < 8; ++qi)
        pm[qi] = fmaxf(pm[qi], __shfl_down(pm[qi], off));
    if (lane == 0)
#pragma unroll
      for (int qi = 0; qi < 8; ++qi) red[wid * 8 + qi] = pm[qi];
    __syncthreads();
    if (t < 8)
      mrow[t] =
          fmaxf(fmaxf(red[t], red[8 + t]), fmaxf(red[16 + t], red[24 + t]));
    __syncthreads();

    // exp + row sum
    float ps[8];
#pragma unroll
    for (int qi = 0; qi < 8; ++qi) {
      float m = mrow[qi];
      float a = 0.f;
#pragma unroll
      for (int j = 0; j < 8; ++j) {
        float e = __expf(s[qi][j] - m);
        s[qi][j] = e;
        a += e;
      }
      ps[qi] = a;
    }
#pragma unroll
    for (int off = 32; off > 0; off >>= 1)
#pragma unroll
      for (int qi = 0; qi < 8; ++qi) ps[qi] += __shfl_down(ps[qi], off);
    if (lane == 0)
#pragma unroll
      for (int qi = 0; qi < 8; ++qi) red[wid * 8 + qi] = ps[qi];
    __syncthreads();
    if (t < 8) lrow[t] = red[t] + red[8 + t] + red[16 + t] + red[24 + t];
    __syncthreads();

    // normalize (guarded), accumulate head-mean; p stays in s[][]
#pragma unroll
    for (int qi = 0; qi < 8; ++qi) {
      float l = lrow[qi];
      float inv = (l > 0.f) ? 1.0f / l : 0.f;
#pragma unroll
      for (int j = 0; j < 8; ++j) {
        float p = s[qi][j] * inv;
        aw[qi][j] += 0.125f * p;
        s[qi][j] = p;
      }
    }

    // ctx = P @ V in two k-halves (P through 32 KB LDS)
    const int d = lane;
    const int g = wid;
    float cacc[8] = {};
#pragma unroll
    for (int half = 0; half < 2; ++half) {
      __syncthreads();  // prior p_lds reads (prev half / prev head) done
#pragma unroll
      for (int j4 = 0; j4 < 4; ++j4)
#pragma unroll
        for (int qi = 0; qi < 8; ++qi)
          p_lds[qi * 1024 + t + 256 * j4] = s[qi][half * 4 + j4];
      __syncthreads();
      const int vbase = ((b * NH + h) * KL + half * 1024) * DH;
      for (int k = g * 256; k < g * 256 + 256; k += 4) {
        float vf[4];
#pragma unroll
        for (int i = 0; i < 4; ++i) vf[i] = b2f(vw[vbase + (k + i) * DH + d]);
#pragma unroll
        for (int qi = 0; qi < 8; ++qi) {
          float4 pv = *(float4*)&p_lds[qi * 1024 + k];
          cacc[qi] +=
              pv.x * vf[0] + pv.y * vf[1] + pv.z * vf[2] + pv.w * vf[3];
        }
      }
    }
    __syncthreads();
#pragma unroll
    for (int qi = 0; qi < 8; ++qi) ctxp[(g * 8 + qi) * 64 + d] = cacc[qi];
    __syncthreads();
    for (int i = t; i < 512; i += 256) {
      int qi = i >> 6, dd = i & 63;
      float sum = ctxp[qi * 64 + dd] + ctxp[(8 + qi) * 64 + dd] +
                  ctxp[(16 + qi) * 64 + dd] + ctxp[(24 + qi) * 64 + dd];
      ctx_out[(b * QL + q0 + qi) * EE + h * DH + dd] = f2b(sum);
    }
    __syncthreads();
  }

  // attn_weights = mean over heads (fp32 out)
#pragma unroll
  for (int qi = 0; qi < 8; ++qi)
#pragma unroll
    for (int j = 0; j < 8; ++j)
      aw_out[(b * QL + q0 + qi) * KL + t + 256 * j] = aw[qi][j];
}

// ---------------- residual + LayerNorm (row = 512) --------------------------
// x: bf16 ws. res: fp32 x_key rows (res_is_xkey) else bf16 ws.
// out: fp32 d_out (out_f32) else bf16 ws.
__global__ __launch_bounds__(256) void ln_res(
    const u16t* __restrict__ x, const u16t* __restrict__ res_b,
    const float* __restrict__ res_f, int res_is_xkey,
    const float* __restrict__ g, const float* __restrict__ bb,
    u16t* __restrict__ out_b, float* __restrict__ out_f, int out_f32) {
  __shared__ float red[4];
  int row = blockIdx.x;
  int t = threadIdx.x;
  int base = row * EE;
  float r0, r1;
  if (res_is_xkey) {
    int b = row >> 10, qq = row & 1023;
    int rbase = (b * KL + QL + qq) * EE;
    r0 = res_f[rbase + t];
    r1 = res_f[rbase + t + 256];
  } else {
    r0 = b2f(res_b[base + t]);
    r1 = b2f(res_b[base + t + 256]);
  }
  float a0 = b2f(x[base + t]) + r0;
  float a1 = b2f(x[base + t + 256]) + r1;
  float sv = a0 + a1;
#pragma unroll
  for (int off = 32; off > 0; off >>= 1) sv += __shfl_down(sv, off);
  if ((t & 63) == 0) red[t >> 6] = sv;
  __syncthreads();
  float mu = (red[0] + red[1] + red[2] + red[3]) * (1.0f / 512.0f);
  __syncthreads();
  float d0 = a0 - mu, d1 = a1 - mu;
  float vv = d0 * d0 + d1 * d1;
#pragma unroll
  for (int off = 32; off > 0; off >>= 1) vv += __shfl_down(vv, off);
  if ((t & 63) == 0) red[t >> 6] = vv;
  __syncthreads();
  float var = (red[0] + red[1] + red[2] + red[3]) * (1.0f / 512.0f);
  float rs = rsqrtf(fmaxf(var, 0.f) + 1e-5f);
  float o0 = d0 * rs * g[t] + bb[t];
  float o1 = d1 * rs * g[t + 256] + bb[t + 256];
  if (out_f32) {
    out_f[base + t] = o0;
    out_f[base + t + 256] = o1;
  } else {
    out_b[base + t] = f2b(o0);
    out_b[base + t + 256] = f2b(o1);
  }
}

extern "C" void kernel_launch(void* const* d_in, const int* in_sizes, int n_in,
                              void* d_out, int out_size, void* d_ws,
                              size_t ws_size, hipStream_t stream) {
  const float* x_key = (const float*)d_in[0];
  const float* in_proj_w = (const float*)d_in[1];
  const float* in_proj_b = (const float*)d_in[2];
  const float* out_w = (const float*)d_in[3];
  const float* out_b = (const float*)d_in[4];
  const float* ln1_g = (const float*)d_in[5];
  const float* ln1_b = (const float*)d_in[6];
  const float* w1 = (const float*)d_in[7];
  const float* b1 = (const float*)d_in[8];
  const float* w2 = (const float*)d_in[9];
  const float* b2 = (const float*)d_in[10];
  const float* ln2_g = (const float*)d_in[11];
  const float* ln2_b = (const float*)d_in[12];
  const void* kpm = d_in[14];

  float* out = (float*)d_out;
  u16t* ws = (u16t*)d_ws;

  // workspace layout (bf16 elements), 96 MB with reuse:
  //   q   [ 8,388,608] -> reused as ao
  //   k   [16,777,216] -> reused as h1
  //   v   [16,777,216] -> reused as ff
  //   ctx [ 8,388,608] -> reused as t (LN1 output)
  u16t* q_ws = ws;
  u16t* k_ws = ws + 8388608;
  u16t* v_ws = ws + 25165824;
  u16t* ctx_ws = ws + 41943040;
  u16t* ao_ws = q_ws;
  u16t* t_ws = ctx_ws;
  u16t* h1_ws = k_ws;
  u16t* ff_ws = v_ws;
  float* aw_out = out + (NB * QL * EE);  // output0 first, attn_weights after

  gemm_qkv<<<dim3(24, 512), 256, 0, stream>>>(x_key, in_proj_w, in_proj_b,
                                              q_ws, k_ws, v_ws);
  attn_kernel<<<dim3(128, NB), 256, 0, stream>>>(q_ws, k_ws, v_ws,
                                                 (const int*)kpm,
                                                 (const unsigned char*)kpm,
                                                 ctx_ws, aw_out);
  gemm_bias<<<dim3(8, 256), 256, 0, stream>>>(ctx_ws, out_w, out_b, ao_ws,
                                              NB * QL, EE, EE, 0);
  ln_res<<<NB * QL, 256, 0, stream>>>(ao_ws, nullptr, x_key, 1, ln1_g, ln1_b,
                                      t_ws, nullptr, 0);
  gemm_bias<<<dim3(8, 256), 256, 0, stream>>>(t_ws, w1, b1, h1_ws, NB * QL, EE,
                                              EE, 1);
  gemm_bias<<<dim3(8, 256), 256, 0, stream>>>(h1_ws, w2, b2, ff_ws, NB * QL,
                                              EE, EE, 0);
  ln_res<<<NB * QL, 256, 0, stream>>>(ff_ws, t_ws, nullptr, 0, ln2_g, ln2_b,
                                      nullptr, out, 1);
}

// Round 4
// 1832.492 us; speedup vs baseline: 6.1915x; 6.1915x over previous
//
#include <hip/hip_runtime.h>

typedef unsigned short u16t;
typedef __attribute__((ext_vector_type(4))) unsigned short us4;
typedef __attribute__((ext_vector_type(8))) unsigned short us8;
typedef __attribute__((ext_vector_type(8))) short s8v;   // MFMA A/B frag (8 bf16)
typedef __attribute__((ext_vector_type(4))) float f4v;   // MFMA C/D frag

#define NB 16
#define KL 2048
#define QL 1024
#define EE 512
#define NH 8
#define DH 64

__device__ __forceinline__ float b2f(u16t u) {
  return __uint_as_float(((unsigned)u) << 16);
}
__device__ __forceinline__ u16t f2b(float f) {
  unsigned u = __float_as_uint(f);
  u += 0x7fffu + ((u >> 16) & 1u);
  return (u16t)(u >> 16);
}

__device__ __forceinline__ int detect_mode(const int* kpm_i) {
  // 0=byte bool, 1=int32, 2=int64 (OOB-safe: reads 256 B)
  bool small = true, oddzero = true, evenone = false;
  for (int i = 0; i < 64; ++i) {
    unsigned v = (unsigned)kpm_i[i];
    if (v > 1u) small = false;
    if ((i & 1) && v != 0u) oddzero = false;
    if (!(i & 1) && v == 1u) evenone = true;
  }
  return !small ? 0 : ((oddzero && evenone) ? 2 : 1);
}

// ---------------- QKV projection: A,W fp32; scatter bf16. V stored (d,key) -
__global__ __launch_bounds__(256) void gemm_qkv(
    const float* __restrict__ A, const float* __restrict__ W,
    const float* __restrict__ bias, u16t* __restrict__ q_ws,
    u16t* __restrict__ k_ws, u16t* __restrict__ v_ws) {
  __shared__ float As[32][64];
  __shared__ float Bs[32][64];
  const int Kd = EE;
  int t = threadIdx.x;
  int n0 = blockIdx.x * 64, m0 = blockIdx.y * 64;
  int tx = t & 15, ty = t >> 4;
  int lr = t >> 2, lc = (t & 3) * 8;
  float acc[4][4] = {};
  for (int kc = 0; kc < Kd; kc += 32) {
    float4 a0 = *(const float4*)&A[(m0 + lr) * Kd + kc + lc];
    float4 a1 = *(const float4*)&A[(m0 + lr) * Kd + kc + lc + 4];
    float4 w0 = *(const float4*)&W[(n0 + lr) * Kd + kc + lc];
    float4 w1 = *(const float4*)&W[(n0 + lr) * Kd + kc + lc + 4];
    __syncthreads();
    As[lc + 0][lr] = a0.x; As[lc + 1][lr] = a0.y;
    As[lc + 2][lr] = a0.z; As[lc + 3][lr] = a0.w;
    As[lc + 4][lr] = a1.x; As[lc + 5][lr] = a1.y;
    As[lc + 6][lr] = a1.z; As[lc + 7][lr] = a1.w;
    Bs[lc + 0][lr] = w0.x; Bs[lc + 1][lr] = w0.y;
    Bs[lc + 2][lr] = w0.z; Bs[lc + 3][lr] = w0.w;
    Bs[lc + 4][lr] = w1.x; Bs[lc + 5][lr] = w1.y;
    Bs[lc + 6][lr] = w1.z; Bs[lc + 7][lr] = w1.w;
    __syncthreads();
#pragma unroll
    for (int k = 0; k < 32; ++k) {
      float4 a = *(float4*)&As[k][ty * 4];
      float4 b = *(float4*)&Bs[k][tx * 4];
      float ar[4] = {a.x, a.y, a.z, a.w};
      float br[4] = {b.x, b.y, b.z, b.w};
#pragma unroll
      for (int i = 0; i < 4; ++i)
#pragma unroll
        for (int j = 0; j < 4; ++j) acc[i][j] += ar[i] * br[j];
    }
  }
  int sec = n0 >> 9;       // 0=q, 1=k, 2=v (uniform per block)
  int hh = (n0 >> 6) & 7;  // head (uniform per block)
#pragma unroll
  for (int i = 0; i < 4; ++i) {
    int m = m0 + ty * 4 + i;
    int bb_ = m >> 11, pos = m & 2047;
#pragma unroll
    for (int j = 0; j < 4; ++j) {
      int n = n0 + tx * 4 + j;
      int dd = n & 63;
      u16t o = f2b(acc[i][j] + bias[n]);
      if (sec == 0) {
        if (pos >= QL) q_ws[((bb_ * NH + hh) * QL + pos - QL) * DH + dd] = o;
      } else if (sec == 1) {
        k_ws[((bb_ * NH + hh) * KL + pos) * DH + dd] = o;
      } else {
        // transposed: [b,h,d,key] so PV B-fragments load contiguously
        v_ws[((bb_ * NH + hh) * DH + dd) * KL + pos] = o;
      }
    }
  }
}

// ---- tiled GEMM: C[M,N] = A[M,K](bf16) @ W[N,K](fp32)^T + bias, C bf16 ----
__global__ __launch_bounds__(256) void gemm_bias(
    const u16t* __restrict__ A, const float* __restrict__ W,
    const float* __restrict__ bias, u16t* __restrict__ C,
    int M, int N, int Kd, int relu) {
  __shared__ float As[32][64];
  __shared__ float Bs[32][64];
  int t = threadIdx.x;
  int n0 = blockIdx.x * 64, m0 = blockIdx.y * 64;
  int tx = t & 15, ty = t >> 4;
  int lr = t >> 2, lc = (t & 3) * 8;
  float acc[4][4] = {};
  for (int kc = 0; kc < Kd; kc += 32) {
    us8 av = *(const us8*)&A[(m0 + lr) * Kd + kc + lc];
    float4 w0 = *(const float4*)&W[(n0 + lr) * Kd + kc + lc];
    float4 w1 = *(const float4*)&W[(n0 + lr) * Kd + kc + lc + 4];
    __syncthreads();
#pragma unroll
    for (int j = 0; j < 8; ++j) As[lc + j][lr] = b2f(av[j]);
    Bs[lc + 0][lr] = w0.x; Bs[lc + 1][lr] = w0.y;
    Bs[lc + 2][lr] = w0.z; Bs[lc + 3][lr] = w0.w;
    Bs[lc + 4][lr] = w1.x; Bs[lc + 5][lr] = w1.y;
    Bs[lc + 6][lr] = w1.z; Bs[lc + 7][lr] = w1.w;
    __syncthreads();
#pragma unroll
    for (int k = 0; k < 32; ++k) {
      float4 a = *(float4*)&As[k][ty * 4];
      float4 b = *(float4*)&Bs[k][tx * 4];
      float ar[4] = {a.x, a.y, a.z, a.w};
      float br[4] = {b.x, b.y, b.z, b.w};
#pragma unroll
      for (int i = 0; i < 4; ++i)
#pragma unroll
        for (int j = 0; j < 4; ++j) acc[i][j] += ar[i] * br[j];
    }
  }
#pragma unroll
  for (int i = 0; i < 4; ++i) {
    int m = m0 + ty * 4 + i;
#pragma unroll
    for (int j = 0; j < 4; ++j) {
      int n = n0 + tx * 4 + j;
      float v = acc[i][j] + bias[n];
      if (relu) v = fmaxf(v, 0.f);
      C[m * N + n] = f2b(v);
    }
  }
}

// ---------------- flash attention fwd: block=(32 q-rows, b*h) --------------
// 4 waves, each owns interleaved 64-key chunks with private online-softmax
// state; merged via LDS. Writes ctx (bf16, [B,Q,E]) and per-row M,L (fp32).
__global__ __launch_bounds__(256) void attn_fwd(
    const u16t* __restrict__ qw, const u16t* __restrict__ kw,
    const u16t* __restrict__ vw, const int* kpm_i, const unsigned char* kpm_b,
    u16t* __restrict__ ctx_out, float* __restrict__ m_ws,
    float* __restrict__ l_ws) {
  const int q0 = blockIdx.x * 32;
  const int bh = blockIdx.y;
  const int b = bh >> 3, h = bh & 7;
  const int t = threadIdx.x;
  const int lane = t & 63, w = t >> 6;
  const int col = lane & 15, quad = lane >> 4;

  __shared__ unsigned char padb[KL];
  __shared__ u16t plds[4][2][16][72];   // wave-private P tiles, +8 pad
  __shared__ float ctxm[4][32][64];
  __shared__ float mlm[4][2][32];
  __shared__ float Lrow[32], ewf[4][32];
  __shared__ int mode_s;

  if (t == 0) mode_s = detect_mode(kpm_i);
  __syncthreads();
  const int mode = mode_s;
  for (int i = t; i < KL; i += 256) {
    int idx = b * KL + i;
    padb[i] = (mode == 0)
                  ? (kpm_b[idx] != 0)
                  : (mode == 1 ? (kpm_i[idx] != 0) : (kpm_i[2 * idx] != 0));
  }
  __syncthreads();

  // Q fragments (A-layout): lane holds Q[q0+st*16+col][quad*8+j (+32*half)]
  s8v qa[2][2];
#pragma unroll
  for (int st = 0; st < 2; ++st)
#pragma unroll
    for (int hf = 0; hf < 2; ++hf)
      qa[st][hf] = *(const s8v*)&qw[(bh * QL + q0 + st * 16 + col) * DH +
                                    quad * 8 + 32 * hf];

  f4v cacc[2][4];
#pragma unroll
  for (int st = 0; st < 2; ++st)
#pragma unroll
    for (int dt = 0; dt < 4; ++dt) cacc[st][dt] = (f4v){0.f, 0.f, 0.f, 0.f};
  float mr[2][4], lr[2][4];
#pragma unroll
  for (int st = 0; st < 2; ++st)
#pragma unroll
    for (int r = 0; r < 4; ++r) { mr[st][r] = -1.0e30f; lr[st][r] = 0.f; }

  const int qmaxk = q0 + 31 + QL;  // max unmasked key in this block
  const f4v zf = {0.f, 0.f, 0.f, 0.f};

  for (int i = 0; i < 8; ++i) {
    const int kc = (i * 4 + w) * 64;  // interleaved for load balance
    if (kc > qmaxk) continue;         // fully causal-masked chunk

    // ---- S = Q K^T for 4 key-subtiles, both stripes
    f4v sts[2][4];
#pragma unroll
    for (int tt = 0; tt < 4; ++tt) {
      const u16t* kp = &kw[(bh * KL + kc + tt * 16 + col) * DH + quad * 8];
      s8v kb0 = *(const s8v*)kp;
      s8v kb1 = *(const s8v*)(kp + 32);
#pragma unroll
      for (int st = 0; st < 2; ++st) {
        f4v c = __builtin_amdgcn_mfma_f32_16x16x32_bf16(qa[st][0], kb0, zf, 0, 0, 0);
        sts[st][tt] =
            __builtin_amdgcn_mfma_f32_16x16x32_bf16(qa[st][1], kb1, c, 0, 0, 0);
      }
    }

    // ---- online softmax per stripe
#pragma unroll
    for (int st = 0; st < 2; ++st) {
      float cmax[4] = {-1.0e30f, -1.0e30f, -1.0e30f, -1.0e30f};
#pragma unroll
      for (int tt = 0; tt < 4; ++tt) {
        int key = kc + tt * 16 + col;
        bool pad = padb[key] != 0;
#pragma unroll
        for (int r = 0; r < 4; ++r) {
          int qrow = q0 + st * 16 + quad * 4 + r;
          bool al = (key <= qrow + QL) && (!pad || key == qrow + QL);
          float v = al ? sts[st][tt][r] * 0.125f : -1.0e30f;
          sts[st][tt][r] = v;
          cmax[r] = fmaxf(cmax[r], v);
        }
      }
#pragma unroll
      for (int mk = 1; mk < 16; mk <<= 1)
#pragma unroll
        for (int r = 0; r < 4; ++r)
          cmax[r] = fmaxf(cmax[r], __shfl_xor(cmax[r], mk, 16));
      float alpha[4], rsum[4];
#pragma unroll
      for (int r = 0; r < 4; ++r) {
        float mn = fmaxf(mr[st][r], cmax[r]);
        alpha[r] = __expf(mr[st][r] - mn);
        mr[st][r] = mn;
        rsum[r] = 0.f;
      }
#pragma unroll
      for (int tt = 0; tt < 4; ++tt)
#pragma unroll
        for (int r = 0; r < 4; ++r) {
          float v = sts[st][tt][r];
          float p = (v > -1.0e29f) ? __expf(v - mr[st][r]) : 0.f;
          sts[st][tt][r] = p;
          rsum[r] += p;
        }
#pragma unroll
      for (int mk = 1; mk < 16; mk <<= 1)
#pragma unroll
        for (int r = 0; r < 4; ++r) rsum[r] += __shfl_xor(rsum[r], mk, 16);
#pragma unroll
      for (int r = 0; r < 4; ++r) {
        lr[st][r] = lr[st][r] * alpha[r] + rsum[r];
#pragma unroll
        for (int dt = 0; dt < 4; ++dt) cacc[st][dt][r] *= alpha[r];
      }
      // publish P (C-layout -> LDS)
#pragma unroll
      for (int tt = 0; tt < 4; ++tt)
#pragma unroll
        for (int r = 0; r < 4; ++r)
          plds[w][st][quad * 4 + r][tt * 16 + col] = f2b(sts[st][tt][r]);
    }

    // ---- ctx += P V (A-layout read back; wave-private, waitcnt only)
    s8v pa[2][2];
#pragma unroll
    for (int st = 0; st < 2; ++st)
#pragma unroll
      for (int hf = 0; hf < 2; ++hf)
        pa[st][hf] = *(const s8v*)&plds[w][st][col][hf * 32 + quad * 8];
#pragma unroll
    for (int dt = 0; dt < 4; ++dt) {
      const u16t* vp = &vw[(bh * DH + dt * 16 + col) * KL + kc + quad * 8];
      s8v vb0 = *(const s8v*)vp;
      s8v vb1 = *(const s8v*)(vp + 32);
#pragma unroll
      for (int st = 0; st < 2; ++st) {
        cacc[st][dt] = __builtin_amdgcn_mfma_f32_16x16x32_bf16(
            pa[st][0], vb0, cacc[st][dt], 0, 0, 0);
        cacc[st][dt] = __builtin_amdgcn_mfma_f32_16x16x32_bf16(
            pa[st][1], vb1, cacc[st][dt], 0, 0, 0);
      }
    }
  }

  // ---- merge 4 wave partials
#pragma unroll
  for (int st = 0; st < 2; ++st)
#pragma unroll
    for (int dt = 0; dt < 4; ++dt)
#pragma unroll
      for (int r = 0; r < 4; ++r)
        ctxm[w][st * 16 + quad * 4 + r][dt * 16 + col] = cacc[st][dt][r];
  if (col == 0) {
#pragma unroll
    for (int st = 0; st < 2; ++st)
#pragma unroll
      for (int r = 0; r < 4; ++r) {
        mlm[w][0][st * 16 + quad * 4 + r] = mr[st][r];
        mlm[w][1][st * 16 + quad * 4 + r] = lr[st][r];
      }
  }
  __syncthreads();
  if (t < 32) {
    int q = t;
    float M = mlm[0][0][q];
#pragma unroll
    for (int ww = 1; ww < 4; ++ww) M = fmaxf(M, mlm[ww][0][q]);
    float L = 0.f;
#pragma unroll
    for (int ww = 0; ww < 4; ++ww) {
      float e = __expf(mlm[ww][0][q] - M);
      ewf[ww][q] = e;
      L += mlm[ww][1][q] * e;
    }
    Lrow[q] = L;
    m_ws[bh * QL + q0 + q] = M;
    l_ws[bh * QL + q0 + q] = L;
  }
  __syncthreads();
  for (int i = t; i < 2048; i += 256) {
    int q = i >> 6, d = i & 63;
    float v = ctxm[0][q][d] * ewf[0][q] + ctxm[1][q][d] * ewf[1][q] +
              ctxm[2][q][d] * ewf[2][q] + ctxm[3][q][d] * ewf[3][q];
    v /= Lrow[q];
    ctx_out[(b * QL + q0 + q) * EE + h * DH + d] = f2b(v);
  }
}

// ---------------- attn weights: mean over heads of P, recomputed -----------
// block=(32 q-rows, 128 keys, b); wave owns 32 keys; loops 8 heads.
__global__ __launch_bounds__(256) void attn_aw(
    const u16t* __restrict__ qw, const u16t* __restrict__ kw,
    const int* kpm_i, const unsigned char* kpm_b,
    const float* __restrict__ m_ws, const float* __restrict__ l_ws,
    float* __restrict__ aw_out) {
  const int q0 = blockIdx.x * 32;
  const int k0 = blockIdx.y * 128;
  const int b = blockIdx.z;
  const int t = threadIdx.x;
  const int lane = t & 63, w = t >> 6;
  const int col = lane & 15, quad = lane >> 4;
  const int qmaxk = q0 + 31 + QL;

  if (k0 > qmaxk) {  // fully causal-masked tile: zeros
    for (int i = t; i < 32 * 128; i += 256) {
      int q = i >> 7, c = i & 127;
      aw_out[(b * QL + q0 + q) * KL + k0 + c] = 0.f;
    }
    return;
  }

  __shared__ unsigned char padb[128];
  __shared__ int mode_s;
  if (t == 0) mode_s = detect_mode(kpm_i);
  __syncthreads();
  const int mode = mode_s;
  if (t < 128) {
    int idx = b * KL + k0 + t;
    padb[t] = (mode == 0)
                  ? (kpm_b[idx] != 0)
                  : (mode == 1 ? (kpm_i[idx] != 0) : (kpm_i[2 * idx] != 0));
  }
  __syncthreads();

  const int kt = k0 + w * 32;
  const f4v zf = {0.f, 0.f, 0.f, 0.f};
  f4v acc[2][2];
#pragma unroll
  for (int st = 0; st < 2; ++st)
#pragma unroll
    for (int tt = 0; tt < 2; ++tt) acc[st][tt] = zf;

  for (int h = 0; h < NH; ++h) {
    const int bh = b * NH + h;
    s8v qa[2][2];
#pragma unroll
    for (int st = 0; st < 2; ++st)
#pragma unroll
      for (int hf = 0; hf < 2; ++hf)
        qa[st][hf] = *(const s8v*)&qw[(bh * QL + q0 + st * 16 + col) * DH +
                                      quad * 8 + 32 * hf];
    float Mv[2][4], Li[2][4];
#pragma unroll
    for (int st = 0; st < 2; ++st)
#pragma unroll
      for (int r = 0; r < 4; ++r) {
        int q = q0 + st * 16 + quad * 4 + r;
        Mv[st][r] = m_ws[bh * QL + q];
        Li[st][r] = 1.0f / l_ws[bh * QL + q];
      }
#pragma unroll
    for (int tt = 0; tt < 2; ++tt) {
      const int ktt = kt + tt * 16;
      if (ktt > qmaxk) continue;  // uniform per wave
      const u16t* kp = &kw[(bh * KL + ktt + col) * DH + quad * 8];
      s8v kb0 = *(const s8v*)kp;
      s8v kb1 = *(const s8v*)(kp + 32);
      int key = ktt + col;
      bool pad = padb[key - k0] != 0;
#pragma unroll
      for (int st = 0; st < 2; ++st) {
        f4v c = __builtin_amdgcn_mfma_f32_16x16x32_bf16(qa[st][0], kb0, zf, 0, 0, 0);
        c = __builtin_amdgcn_mfma_f32_16x16x32_bf16(qa[st][1], kb1, c, 0, 0, 0);
#pragma unroll
        for (int r = 0; r < 4; ++r) {
          int qrow = q0 + st * 16 + quad * 4 + r;
          bool al = (key <= qrow + QL) && (!pad || key == qrow + QL);
          float p = al ? __expf(c[r] * 0.125f - Mv[st][r]) * Li[st][r] : 0.f;
          acc[st][tt][r] += 0.125f * p;
        }
      }
    }
  }
#pragma unroll
  for (int st = 0; st < 2; ++st)
#pragma unroll
    for (int tt = 0; tt < 2; ++tt)
#pragma unroll
      for (int r = 0; r < 4; ++r)
        aw_out[(b * QL + q0 + st * 16 + quad * 4 + r) * KL + kt + tt * 16 +
               col] = acc[st][tt][r];
}

// ---------------- residual + LayerNorm (row = 512) --------------------------
__global__ __launch_bounds__(256) void ln_res(
    const u16t* __restrict__ x, const u16t* __restrict__ res_b,
    const float* __restrict__ res_f, int res_is_xkey,
    const float* __restrict__ g, const float* __restrict__ bb,
    u16t* __restrict__ out_b, float* __restrict__ out_f, int out_f32) {
  __shared__ float red[4];
  int row = blockIdx.x;
  int t = threadIdx.x;
  int base = row * EE;
  float r0, r1;
  if (res_is_xkey) {
    int b = row >> 10, qq = row & 1023;
    int rbase = (b * KL + QL + qq) * EE;
    r0 = res_f[rbase + t];
    r1 = res_f[rbase + t + 256];
  } else {
    r0 = b2f(res_b[base + t]);
    r1 = b2f(res_b[base + t + 256]);
  }
  float a0 = b2f(x[base + t]) + r0;
  float a1 = b2f(x[base + t + 256]) + r1;
  float sv = a0 + a1;
#pragma unroll
  for (int off = 32; off > 0; off >>= 1) sv += __shfl_down(sv, off);
  if ((t & 63) == 0) red[t >> 6] = sv;
  __syncthreads();
  float mu = (red[0] + red[1] + red[2] + red[3]) * (1.0f / 512.0f);
  __syncthreads();
  float d0 = a0 - mu, d1 = a1 - mu;
  float vv = d0 * d0 + d1 * d1;
#pragma unroll
  for (int off = 32; off > 0; off >>= 1) vv += __shfl_down(vv, off);
  if ((t & 63) == 0) red[t >> 6] = vv;
  __syncthreads();
  float var = (red[0] + red[1] + red[2] + red[3]) * (1.0f / 512.0f);
  float rs = rsqrtf(fmaxf(var, 0.f) + 1e-5f);
  float o0 = d0 * rs * g[t] + bb[t];
  float o1 = d1 * rs * g[t + 256] + bb[t + 256];
  if (out_f32) {
    out_f[base + t] = o0;
    out_f[base + t + 256] = o1;
  } else {
    out_b[base + t] = f2b(o0);
    out_b[base + t + 256] = f2b(o1);
  }
}

extern "C" void kernel_launch(void* const* d_in, const int* in_sizes, int n_in,
                              void* d_out, int out_size, void* d_ws,
                              size_t ws_size, hipStream_t stream) {
  const float* x_key = (const float*)d_in[0];
  const float* in_proj_w = (const float*)d_in[1];
  const float* in_proj_b = (const float*)d_in[2];
  const float* out_w = (const float*)d_in[3];
  const float* out_b = (const float*)d_in[4];
  const float* ln1_g = (const float*)d_in[5];
  const float* ln1_b = (const float*)d_in[6];
  const float* w1 = (const float*)d_in[7];
  const float* b1 = (const float*)d_in[8];
  const float* w2 = (const float*)d_in[9];
  const float* b2 = (const float*)d_in[10];
  const float* ln2_g = (const float*)d_in[11];
  const float* ln2_b = (const float*)d_in[12];
  const void* kpm = d_in[14];

  float* out = (float*)d_out;
  u16t* ws = (u16t*)d_ws;

  // workspace (bf16 elements): q | k | v^T | ctx | m,l (fp32)  ~102 MB
  u16t* q_ws = ws;                   // 8,388,608
  u16t* k_ws = ws + 8388608;         // 16,777,216
  u16t* v_ws = ws + 25165824;        // 16,777,216 (transposed [b,h,d,key])
  u16t* ctx_ws = ws + 41943040;      // 8,388,608
  float* m_ws = (float*)(ws + 50331648);  // 131,072 floats
  float* l_ws = m_ws + 131072;            // 131,072 floats
  u16t* ao_ws = q_ws;
  u16t* t_ws = ctx_ws;
  u16t* h1_ws = k_ws;
  u16t* ff_ws = v_ws;
  float* aw_out = out + (NB * QL * EE);

  gemm_qkv<<<dim3(24, 512), 256, 0, stream>>>(x_key, in_proj_w, in_proj_b,
                                              q_ws, k_ws, v_ws);
  attn_fwd<<<dim3(QL / 32, NB * NH), 256, 0, stream>>>(
      q_ws, k_ws, v_ws, (const int*)kpm, (const unsigned char*)kpm, ctx_ws,
      m_ws, l_ws);
  attn_aw<<<dim3(QL / 32, KL / 128, NB), 256, 0, stream>>>(
      q_ws, k_ws, (const int*)kpm, (const unsigned char*)kpm, m_ws, l_ws,
      aw_out);
  gemm_bias<<<dim3(8, 256), 256, 0, stream>>>(ctx_ws, out_w, out_b, ao_ws,
                                              NB * QL, EE, EE, 0);
  ln_res<<<NB * QL, 256, 0, stream>>>(ao_ws, nullptr, x_key, 1, ln1_g, ln1_b,
                                      t_ws, nullptr, 0);
  gemm_bias<<<dim3(8, 256), 256, 0, stream>>>(t_ws, w1, b1, h1_ws, NB * QL, EE,
                                              EE, 1);
  gemm_bias<<<dim3(8, 256), 256, 0, stream>>>(h1_ws, w2, b2, ff_ws, NB * QL,
                                              EE, EE, 0);
  ln_res<<<NB * QL, 256, 0, stream>>>(ff_ws, t_ws, nullptr, 0, ln2_g, ln2_b,
                                      nullptr, out, 1);
}

// Round 5
// 1070.482 us; speedup vs baseline: 10.5989x; 1.7118x over previous
//
#include <hip/hip_runtime.h>

typedef unsigned short u16t;
typedef __attribute__((ext_vector_type(4))) unsigned short us4;
typedef __attribute__((ext_vector_type(8))) unsigned short us8;
typedef __attribute__((ext_vector_type(8))) short s8v;   // MFMA A/B frag (8 bf16)
typedef __attribute__((ext_vector_type(4))) float f4v;   // MFMA C/D frag

#define NB 16
#define KL 2048
#define QL 1024
#define EE 512
#define NH 8
#define DH 64

__device__ __forceinline__ float b2f(u16t u) {
  return __uint_as_float(((unsigned)u) << 16);
}
__device__ __forceinline__ u16t f2b(float f) {
  unsigned u = __float_as_uint(f);
  u += 0x7fffu + ((u >> 16) & 1u);
  return (u16t)(u >> 16);
}

__device__ __forceinline__ int detect_mode(const int* kpm_i) {
  // 0=byte bool, 1=int32, 2=int64 (OOB-safe: reads 256 B)
  bool small = true, oddzero = true, evenone = false;
  for (int i = 0; i < 64; ++i) {
    unsigned v = (unsigned)kpm_i[i];
    if (v > 1u) small = false;
    if ((i & 1) && v != 0u) oddzero = false;
    if (!(i & 1) && v == 1u) evenone = true;
  }
  return !small ? 0 : ((oddzero && evenone) ? 2 : 1);
}

// ---------------- fp32 -> bf16 weight conversion (4 matrices, one pass) ----
// float4 regions: in_proj_w 196608 | out_w 65536 | w1 65536 | w2 65536
__global__ __launch_bounds__(256) void cvt_weights(
    const float* __restrict__ wi, const float* __restrict__ wo,
    const float* __restrict__ wf1, const float* __restrict__ wf2,
    u16t* __restrict__ dst) {
  int i = blockIdx.x * 256 + threadIdx.x;  // float4 index, 393216 total
  const float* src;
  int j;
  if (i < 196608) { src = wi; j = i; }
  else if (i < 262144) { src = wo; j = i - 196608; }
  else if (i < 327680) { src = wf1; j = i - 262144; }
  else { src = wf2; j = i - 327680; }
  float4 v = ((const float4*)src)[j];
  us4 o = {f2b(v.x), f2b(v.y), f2b(v.z), f2b(v.w)};
  *(us4*)&dst[i * 4] = o;
}

// ================= MFMA GEMM core macro pieces =============================
// 128x128 tile, BK=32, 4 waves (2x2), each wave 4x4 of 16x16x32 bf16 MFMAs.
// LDS pitch 40 (stride 20 dwords -> 2-way bank alias, free).

// ---------------- QKV: A fp32 [M,512], W bf16 [1536,512]; scatter ----------
__global__ __launch_bounds__(256) void mfma_gemm_qkv(
    const float* __restrict__ A, const u16t* __restrict__ Wb,
    const float* __restrict__ bias, u16t* __restrict__ q_ws,
    u16t* __restrict__ k_ws, u16t* __restrict__ v_ws) {
  const int Kd = EE;
  __shared__ u16t Alds[128 * 40];
  __shared__ u16t Blds[128 * 40];
  const int t = threadIdx.x;
  const int n0 = blockIdx.x * 128, m0 = blockIdx.y * 128;
  const int lane = t & 63, w = t >> 6;
  const int col = lane & 15, quad = lane >> 4;
  const int wm = w & 1, wn = w >> 1;

  const int arow = t >> 1, ahalf = t & 1;   // A: 16 fp32 per thread
  const int wrow = t >> 1, wseg = t & 1;    // W: 16 bf16 per thread

  f4v acc[4][4] = {};

  for (int kc = 0; kc < Kd; kc += 32) {
    const float* ap = &A[(size_t)(m0 + arow) * Kd + kc + ahalf * 16];
    float4 f0 = ((const float4*)ap)[0];
    float4 f1 = ((const float4*)ap)[1];
    float4 f2_ = ((const float4*)ap)[2];
    float4 f3 = ((const float4*)ap)[3];
    const u16t* wp = &Wb[(size_t)(n0 + wrow) * Kd + kc + wseg * 16];
    us8 w0 = *(const us8*)wp;
    us8 w1 = *(const us8*)(wp + 8);
    __syncthreads();
    us8 o0 = {f2b(f0.x), f2b(f0.y), f2b(f0.z), f2b(f0.w),
              f2b(f1.x), f2b(f1.y), f2b(f1.z), f2b(f1.w)};
    us8 o1 = {f2b(f2_.x), f2b(f2_.y), f2b(f2_.z), f2b(f2_.w),
              f2b(f3.x), f2b(f3.y), f2b(f3.z), f2b(f3.w)};
    *(us8*)&Alds[arow * 40 + ahalf * 16] = o0;
    *(us8*)&Alds[arow * 40 + ahalf * 16 + 8] = o1;
    *(us8*)&Blds[wrow * 40 + wseg * 16] = w0;
    *(us8*)&Blds[wrow * 40 + wseg * 16 + 8] = w1;
    __syncthreads();
    s8v af[4], bf[4];
#pragma unroll
    for (int mt = 0; mt < 4; ++mt)
      af[mt] = *(s8v*)&Alds[(wm * 64 + mt * 16 + col) * 40 + quad * 8];
#pragma unroll
    for (int nt = 0; nt < 4; ++nt)
      bf[nt] = *(s8v*)&Blds[(wn * 64 + nt * 16 + col) * 40 + quad * 8];
#pragma unroll
    for (int mt = 0; mt < 4; ++mt)
#pragma unroll
      for (int nt = 0; nt < 4; ++nt)
        acc[mt][nt] = __builtin_amdgcn_mfma_f32_16x16x32_bf16(
            af[mt], bf[nt], acc[mt][nt], 0, 0, 0);
  }

  float bv[4];
#pragma unroll
  for (int nt = 0; nt < 4; ++nt) bv[nt] = bias[n0 + wn * 64 + nt * 16 + col];

#pragma unroll
  for (int nt = 0; nt < 4; ++nt) {
    int n = n0 + wn * 64 + nt * 16 + col;
    int sec = n >> 9, hh = (n >> 6) & 7, dd = n & 63;
#pragma unroll
    for (int mt = 0; mt < 4; ++mt)
#pragma unroll
      for (int r = 0; r < 4; ++r) {
        int m = m0 + wm * 64 + mt * 16 + quad * 4 + r;
        int bb_ = m >> 11, pos = m & 2047;
        u16t o = f2b(acc[mt][nt][r] + bv[nt]);
        if (sec == 0) {
          if (pos >= QL) q_ws[((bb_ * NH + hh) * QL + pos - QL) * DH + dd] = o;
        } else if (sec == 1) {
          k_ws[((bb_ * NH + hh) * KL + pos) * DH + dd] = o;
        } else {
          v_ws[((bb_ * NH + hh) * DH + dd) * KL + pos] = o;  // [b,h,d,key]
        }
      }
  }
}

// ---------------- generic: A bf16 [M,K], W bf16 [N,K]; C bf16 + bias/relu --
__global__ __launch_bounds__(256) void mfma_gemm_bias(
    const u16t* __restrict__ A, const u16t* __restrict__ Wb,
    const float* __restrict__ bias, u16t* __restrict__ C, int M, int N,
    int Kd, int relu) {
  __shared__ u16t Alds[128 * 40];
  __shared__ u16t Blds[128 * 40];
  const int t = threadIdx.x;
  const int n0 = blockIdx.x * 128, m0 = blockIdx.y * 128;
  const int lane = t & 63, w = t >> 6;
  const int col = lane & 15, quad = lane >> 4;
  const int wm = w & 1, wn = w >> 1;
  const int row = t >> 1, seg = t & 1;

  f4v acc[4][4] = {};

  for (int kc = 0; kc < Kd; kc += 32) {
    const u16t* ap = &A[(size_t)(m0 + row) * Kd + kc + seg * 16];
    us8 a0 = *(const us8*)ap;
    us8 a1 = *(const us8*)(ap + 8);
    const u16t* wp = &Wb[(size_t)(n0 + row) * Kd + kc + seg * 16];
    us8 w0 = *(const us8*)wp;
    us8 w1 = *(const us8*)(wp + 8);
    __syncthreads();
    *(us8*)&Alds[row * 40 + seg * 16] = a0;
    *(us8*)&Alds[row * 40 + seg * 16 + 8] = a1;
    *(us8*)&Blds[row * 40 + seg * 16] = w0;
    *(us8*)&Blds[row * 40 + seg * 16 + 8] = w1;
    __syncthreads();
    s8v af[4], bf[4];
#pragma unroll
    for (int mt = 0; mt < 4; ++mt)
      af[mt] = *(s8v*)&Alds[(wm * 64 + mt * 16 + col) * 40 + quad * 8];
#pragma unroll
    for (int nt = 0; nt < 4; ++nt)
      bf[nt] = *(s8v*)&Blds[(wn * 64 + nt * 16 + col) * 40 + quad * 8];
#pragma unroll
    for (int mt = 0; mt < 4; ++mt)
#pragma unroll
      for (int nt = 0; nt < 4; ++nt)
        acc[mt][nt] = __builtin_amdgcn_mfma_f32_16x16x32_bf16(
            af[mt], bf[nt], acc[mt][nt], 0, 0, 0);
  }

  float bv[4];
#pragma unroll
  for (int nt = 0; nt < 4; ++nt) bv[nt] = bias[n0 + wn * 64 + nt * 16 + col];

#pragma unroll
  for (int mt = 0; mt < 4; ++mt)
#pragma unroll
    for (int nt = 0; nt < 4; ++nt) {
      int n = n0 + wn * 64 + nt * 16 + col;
#pragma unroll
      for (int r = 0; r < 4; ++r) {
        int m = m0 + wm * 64 + mt * 16 + quad * 4 + r;
        float v = acc[mt][nt][r] + bv[nt];
        if (relu) v = fmaxf(v, 0.f);
        C[(size_t)m * N + n] = f2b(v);
      }
    }
}

// ---------------- flash attention fwd: block=(32 q-rows, b*h) --------------
__global__ __launch_bounds__(256) void attn_fwd(
    const u16t* __restrict__ qw, const u16t* __restrict__ kw,
    const u16t* __restrict__ vw, const int* kpm_i, const unsigned char* kpm_b,
    u16t* __restrict__ ctx_out, float* __restrict__ m_ws,
    float* __restrict__ l_ws) {
  const int q0 = blockIdx.x * 32;
  const int bh = blockIdx.y;
  const int b = bh >> 3, h = bh & 7;
  const int t = threadIdx.x;
  const int lane = t & 63, w = t >> 6;
  const int col = lane & 15, quad = lane >> 4;

  __shared__ unsigned char padb[KL];
  __shared__ u16t plds[4][2][16][72];
  __shared__ float ctxm[4][32][64];
  __shared__ float mlm[4][2][32];
  __shared__ float Lrow[32], ewf[4][32];
  __shared__ int mode_s;

  if (t == 0) mode_s = detect_mode(kpm_i);
  __syncthreads();
  const int mode = mode_s;
  for (int i = t; i < KL; i += 256) {
    int idx = b * KL + i;
    padb[i] = (mode == 0)
                  ? (kpm_b[idx] != 0)
                  : (mode == 1 ? (kpm_i[idx] != 0) : (kpm_i[2 * idx] != 0));
  }
  __syncthreads();

  s8v qa[2][2];
#pragma unroll
  for (int st = 0; st < 2; ++st)
#pragma unroll
    for (int hf = 0; hf < 2; ++hf)
      qa[st][hf] = *(const s8v*)&qw[(bh * QL + q0 + st * 16 + col) * DH +
                                    quad * 8 + 32 * hf];

  f4v cacc[2][4];
#pragma unroll
  for (int st = 0; st < 2; ++st)
#pragma unroll
    for (int dt = 0; dt < 4; ++dt) cacc[st][dt] = (f4v){0.f, 0.f, 0.f, 0.f};
  float mr[2][4], lr[2][4];
#pragma unroll
  for (int st = 0; st < 2; ++st)
#pragma unroll
    for (int r = 0; r < 4; ++r) { mr[st][r] = -1.0e30f; lr[st][r] = 0.f; }

  const int qmaxk = q0 + 31 + QL;
  const f4v zf = {0.f, 0.f, 0.f, 0.f};

  for (int i = 0; i < 8; ++i) {
    const int kc = (i * 4 + w) * 64;
    if (kc > qmaxk) continue;

    f4v sts[2][4];
#pragma unroll
    for (int tt = 0; tt < 4; ++tt) {
      const u16t* kp = &kw[(bh * KL + kc + tt * 16 + col) * DH + quad * 8];
      s8v kb0 = *(const s8v*)kp;
      s8v kb1 = *(const s8v*)(kp + 32);
#pragma unroll
      for (int st = 0; st < 2; ++st) {
        f4v c = __builtin_amdgcn_mfma_f32_16x16x32_bf16(qa[st][0], kb0, zf, 0, 0, 0);
        sts[st][tt] =
            __builtin_amdgcn_mfma_f32_16x16x32_bf16(qa[st][1], kb1, c, 0, 0, 0);
      }
    }

#pragma unroll
    for (int st = 0; st < 2; ++st) {
      float cmax[4] = {-1.0e30f, -1.0e30f, -1.0e30f, -1.0e30f};
#pragma unroll
      for (int tt = 0; tt < 4; ++tt) {
        int key = kc + tt * 16 + col;
        bool pad = padb[key] != 0;
#pragma unroll
        for (int r = 0; r < 4; ++r) {
          int qrow = q0 + st * 16 + quad * 4 + r;
          bool al = (key <= qrow + QL) && (!pad || key == qrow + QL);
          float v = al ? sts[st][tt][r] * 0.125f : -1.0e30f;
          sts[st][tt][r] = v;
          cmax[r] = fmaxf(cmax[r], v);
        }
      }
#pragma unroll
      for (int mk = 1; mk < 16; mk <<= 1)
#pragma unroll
        for (int r = 0; r < 4; ++r)
          cmax[r] = fmaxf(cmax[r], __shfl_xor(cmax[r], mk, 16));
      float alpha[4], rsum[4];
#pragma unroll
      for (int r = 0; r < 4; ++r) {
        float mn = fmaxf(mr[st][r], cmax[r]);
        alpha[r] = __expf(mr[st][r] - mn);
        mr[st][r] = mn;
        rsum[r] = 0.f;
      }
#pragma unroll
      for (int tt = 0; tt < 4; ++tt)
#pragma unroll
        for (int r = 0; r < 4; ++r) {
          float v = sts[st][tt][r];
          float p = (v > -1.0e29f) ? __expf(v - mr[st][r]) : 0.f;
          sts[st][tt][r] = p;
          rsum[r] += p;
        }
#pragma unroll
      for (int mk = 1; mk < 16; mk <<= 1)
#pragma unroll
        for (int r = 0; r < 4; ++r) rsum[r] += __shfl_xor(rsum[r], mk, 16);
#pragma unroll
      for (int r = 0; r < 4; ++r) {
        lr[st][r] = lr[st][r] * alpha[r] + rsum[r];
#pragma unroll
        for (int dt = 0; dt < 4; ++dt) cacc[st][dt][r] *= alpha[r];
      }
#pragma unroll
      for (int tt = 0; tt < 4; ++tt)
#pragma unroll
        for (int r = 0; r < 4; ++r)
          plds[w][st][quad * 4 + r][tt * 16 + col] = f2b(sts[st][tt][r]);
    }

    s8v pa[2][2];
#pragma unroll
    for (int st = 0; st < 2; ++st)
#pragma unroll
      for (int hf = 0; hf < 2; ++hf)
        pa[st][hf] = *(const s8v*)&plds[w][st][col][hf * 32 + quad * 8];
#pragma unroll
    for (int dt = 0; dt < 4; ++dt) {
      const u16t* vp = &vw[(bh * DH + dt * 16 + col) * KL + kc + quad * 8];
      s8v vb0 = *(const s8v*)vp;
      s8v vb1 = *(const s8v*)(vp + 32);
#pragma unroll
      for (int st = 0; st < 2; ++st) {
        cacc[st][dt] = __builtin_amdgcn_mfma_f32_16x16x32_bf16(
            pa[st][0], vb0, cacc[st][dt], 0, 0, 0);
        cacc[st][dt] = __builtin_amdgcn_mfma_f32_16x16x32_bf16(
            pa[st][1], vb1, cacc[st][dt], 0, 0, 0);
      }
    }
  }

#pragma unroll
  for (int st = 0; st < 2; ++st)
#pragma unroll
    for (int dt = 0; dt < 4; ++dt)
#pragma unroll
      for (int r = 0; r < 4; ++r)
        ctxm[w][st * 16 + quad * 4 + r][dt * 16 + col] = cacc[st][dt][r];
  if (col == 0) {
#pragma unroll
    for (int st = 0; st < 2; ++st)
#pragma unroll
      for (int r = 0; r < 4; ++r) {
        mlm[w][0][st * 16 + quad * 4 + r] = mr[st][r];
        mlm[w][1][st * 16 + quad * 4 + r] = lr[st][r];
      }
  }
  __syncthreads();
  if (t < 32) {
    int q = t;
    float M = mlm[0][0][q];
#pragma unroll
    for (int ww = 1; ww < 4; ++ww) M = fmaxf(M, mlm[ww][0][q]);
    float L = 0.f;
#pragma unroll
    for (int ww = 0; ww < 4; ++ww) {
      float e = __expf(mlm[ww][0][q] - M);
      ewf[ww][q] = e;
      L += mlm[ww][1][q] * e;
    }
    Lrow[q] = L;
    m_ws[bh * QL + q0 + q] = M;
    l_ws[bh * QL + q0 + q] = L;
  }
  __syncthreads();
  for (int i = t; i < 2048; i += 256) {
    int q = i >> 6, d = i & 63;
    float v = ctxm[0][q][d] * ewf[0][q] + ctxm[1][q][d] * ewf[1][q] +
              ctxm[2][q][d] * ewf[2][q] + ctxm[3][q][d] * ewf[3][q];
    v /= Lrow[q];
    ctx_out[(b * QL + q0 + q) * EE + h * DH + d] = f2b(v);
  }
}

// ---------------- attn weights: mean over heads of P, recomputed -----------
__global__ __launch_bounds__(256) void attn_aw(
    const u16t* __restrict__ qw, const u16t* __restrict__ kw,
    const int* kpm_i, const unsigned char* kpm_b,
    const float* __restrict__ m_ws, const float* __restrict__ l_ws,
    float* __restrict__ aw_out) {
  const int q0 = blockIdx.x * 32;
  const int k0 = blockIdx.y * 128;
  const int b = blockIdx.z;
  const int t = threadIdx.x;
  const int lane = t & 63, w = t >> 6;
  const int col = lane & 15, quad = lane >> 4;
  const int qmaxk = q0 + 31 + QL;

  if (k0 > qmaxk) {
    for (int i = t; i < 32 * 128; i += 256) {
      int q = i >> 7, c = i & 127;
      aw_out[(b * QL + q0 + q) * KL + k0 + c] = 0.f;
    }
    return;
  }

  __shared__ unsigned char padb[128];
  __shared__ int mode_s;
  if (t == 0) mode_s = detect_mode(kpm_i);
  __syncthreads();
  const int mode = mode_s;
  if (t < 128) {
    int idx = b * KL + k0 + t;
    padb[t] = (mode == 0)
                  ? (kpm_b[idx] != 0)
                  : (mode == 1 ? (kpm_i[idx] != 0) : (kpm_i[2 * idx] != 0));
  }
  __syncthreads();

  const int kt = k0 + w * 32;
  const f4v zf = {0.f, 0.f, 0.f, 0.f};
  f4v acc[2][2];
#pragma unroll
  for (int st = 0; st < 2; ++st)
#pragma unroll
    for (int tt = 0; tt < 2; ++tt) acc[st][tt] = zf;

  for (int h = 0; h < NH; ++h) {
    const int bh = b * NH + h;
    s8v qa[2][2];
#pragma unroll
    for (int st = 0; st < 2; ++st)
#pragma unroll
      for (int hf = 0; hf < 2; ++hf)
        qa[st][hf] = *(const s8v*)&qw[(bh * QL + q0 + st * 16 + col) * DH +
                                      quad * 8 + 32 * hf];
    float Mv[2][4], Li[2][4];
#pragma unroll
    for (int st = 0; st < 2; ++st)
#pragma unroll
      for (int r = 0; r < 4; ++r) {
        int q = q0 + st * 16 + quad * 4 + r;
        Mv[st][r] = m_ws[bh * QL + q];
        Li[st][r] = 1.0f / l_ws[bh * QL + q];
      }
#pragma unroll
    for (int tt = 0; tt < 2; ++tt) {
      const int ktt = kt + tt * 16;
      if (ktt > qmaxk) continue;
      const u16t* kp = &kw[(bh * KL + ktt + col) * DH + quad * 8];
      s8v kb0 = *(const s8v*)kp;
      s8v kb1 = *(const s8v*)(kp + 32);
      int key = ktt + col;
      bool pad = padb[key - k0] != 0;
#pragma unroll
      for (int st = 0; st < 2; ++st) {
        f4v c = __builtin_amdgcn_mfma_f32_16x16x32_bf16(qa[st][0], kb0, zf, 0, 0, 0);
        c = __builtin_amdgcn_mfma_f32_16x16x32_bf16(qa[st][1], kb1, c, 0, 0, 0);
#pragma unroll
        for (int r = 0; r < 4; ++r) {
          int qrow = q0 + st * 16 + quad * 4 + r;
          bool al = (key <= qrow + QL) && (!pad || key == qrow + QL);
          float p = al ? __expf(c[r] * 0.125f - Mv[st][r]) * Li[st][r] : 0.f;
          acc[st][tt][r] += 0.125f * p;
        }
      }
    }
  }
#pragma unroll
  for (int st = 0; st < 2; ++st)
#pragma unroll
    for (int tt = 0; tt < 2; ++tt)
#pragma unroll
      for (int r = 0; r < 4; ++r)
        aw_out[(b * QL + q0 + st * 16 + quad * 4 + r) * KL + kt + tt * 16 +
               col] = acc[st][tt][r];
}

// ---------------- residual + LayerNorm (row = 512) --------------------------
__global__ __launch_bounds__(256) void ln_res(
    const u16t* __restrict__ x, const u16t* __restrict__ res_b,
    const float* __restrict__ res_f, int res_is_xkey,
    const float* __restrict__ g, const float* __restrict__ bb,
    u16t* __restrict__ out_b, float* __restrict__ out_f, int out_f32) {
  __shared__ float red[4];
  int row = blockIdx.x;
  int t = threadIdx.x;
  int base = row * EE;
  float r0, r1;
  if (res_is_xkey) {
    int b = row >> 10, qq = row & 1023;
    int rbase = (b * KL + QL + qq) * EE;
    r0 = res_f[rbase + t];
    r1 = res_f[rbase + t + 256];
  } else {
    r0 = b2f(res_b[base + t]);
    r1 = b2f(res_b[base + t + 256]);
  }
  float a0 = b2f(x[base + t]) + r0;
  float a1 = b2f(x[base + t + 256]) + r1;
  float sv = a0 + a1;
#pragma unroll
  for (int off = 32; off > 0; off >>= 1) sv += __shfl_down(sv, off);
  if ((t & 63) == 0) red[t >> 6] = sv;
  __syncthreads();
  float mu = (red[0] + red[1] + red[2] + red[3]) * (1.0f / 512.0f);
  __syncthreads();
  float d0 = a0 - mu, d1 = a1 - mu;
  float vv = d0 * d0 + d1 * d1;
#pragma unroll
  for (int off = 32; off > 0; off >>= 1) vv += __shfl_down(vv, off);
  if ((t & 63) == 0) red[t >> 6] = vv;
  __syncthreads();
  float var = (red[0] + red[1] + red[2] + red[3]) * (1.0f / 512.0f);
  float rs = rsqrtf(fmaxf(var, 0.f) + 1e-5f);
  float o0 = d0 * rs * g[t] + bb[t];
  float o1 = d1 * rs * g[t + 256] + bb[t + 256];
  if (out_f32) {
    out_f[base + t] = o0;
    out_f[base + t + 256] = o1;
  } else {
    out_b[base + t] = f2b(o0);
    out_b[base + t + 256] = f2b(o1);
  }
}

extern "C" void kernel_launch(void* const* d_in, const int* in_sizes, int n_in,
                              void* d_out, int out_size, void* d_ws,
                              size_t ws_size, hipStream_t stream) {
  const float* x_key = (const float*)d_in[0];
  const float* in_proj_w = (const float*)d_in[1];
  const float* in_proj_b = (const float*)d_in[2];
  const float* out_w = (const float*)d_in[3];
  const float* out_b = (const float*)d_in[4];
  const float* ln1_g = (const float*)d_in[5];
  const float* ln1_b = (const float*)d_in[6];
  const float* w1 = (const float*)d_in[7];
  const float* b1 = (const float*)d_in[8];
  const float* w2 = (const float*)d_in[9];
  const float* b2 = (const float*)d_in[10];
  const float* ln2_g = (const float*)d_in[11];
  const float* ln2_b = (const float*)d_in[12];
  const void* kpm = d_in[14];

  float* out = (float*)d_out;
  u16t* ws = (u16t*)d_ws;

  // workspace (u16 elems), ~100 MB total:
  // wb (4 weights bf16) | q | k | v^T | ctx | m,l(fp32)
  u16t* wb_inproj = ws;                       //   786,432
  u16t* wb_out = ws + 786432;                 //   262,144
  u16t* wb_w1 = ws + 1048576;                 //   262,144
  u16t* wb_w2 = ws + 1310720;                 //   262,144
  u16t* q_ws = ws + 1572864;                  // 8,388,608
  u16t* k_ws = ws + 9961472;                  // 16,777,216
  u16t* v_ws = ws + 26738688;                 // 16,777,216 ([b,h,d,key])
  u16t* ctx_ws = ws + 43515904;               // 8,388,608
  float* m_ws = (float*)(ws + 51904512);      // 131,072 fp32
  float* l_ws = m_ws + 131072;                // 131,072 fp32
  u16t* ao_ws = q_ws;                         // after attn_aw no longer needs q
  u16t* t_ws = ctx_ws;
  u16t* h1_ws = k_ws;
  u16t* ff_ws = v_ws;
  float* aw_out = out + (NB * QL * EE);

  cvt_weights<<<1536, 256, 0, stream>>>(in_proj_w, out_w, w1, w2, wb_inproj);
  mfma_gemm_qkv<<<dim3(12, 256), 256, 0, stream>>>(x_key, wb_inproj,
                                                   in_proj_b, q_ws, k_ws,
                                                   v_ws);
  attn_fwd<<<dim3(QL / 32, NB * NH), 256, 0, stream>>>(
      q_ws, k_ws, v_ws, (const int*)kpm, (const unsigned char*)kpm, ctx_ws,
      m_ws, l_ws);
  attn_aw<<<dim3(QL / 32, KL / 128, NB), 256, 0, stream>>>(
      q_ws, k_ws, (const int*)kpm, (const unsigned char*)kpm, m_ws, l_ws,
      aw_out);
  mfma_gemm_bias<<<dim3(4, 128), 256, 0, stream>>>(ctx_ws, wb_out, out_b,
                                                   ao_ws, NB * QL, EE, EE, 0);
  ln_res<<<NB * QL, 256, 0, stream>>>(ao_ws, nullptr, x_key, 1, ln1_g, ln1_b,
                                      t_ws, nullptr, 0);
  mfma_gemm_bias<<<dim3(4, 128), 256, 0, stream>>>(t_ws, wb_w1, b1, h1_ws,
                                                   NB * QL, EE, EE, 1);
  mfma_gemm_bias<<<dim3(4, 128), 256, 0, stream>>>(h1_ws, wb_w2, b2, ff_ws,
                                                   NB * QL, EE, EE, 0);
  ln_res<<<NB * QL, 256, 0, stream>>>(ff_ws, t_ws, nullptr, 0, ln2_g, ln2_b,
                                      nullptr, out, 1);
}